// Round 3
// baseline (176.143 us; speedup 1.0000x reference)
//
#include <hip/hip_runtime.h>

// Workspace layout (float offsets), ~925 KB total.
#define WS_SC1    0         // [26][5][32][32] pooled conv1
#define WS_FEAT   133120    // [26][1960]      pooled conv2 (flattened)
#define WS_FC1P   184080    // [26][500]       fc1 partial (class part + bias)
#define WS_FC2P   197080    // [125][64][4]    fc2 weights packed float4 by (j4,e)
#define WS_AFLAT  229080    // [64][4]         A_B + A_C
#define WS_WX     229336    // [500][2]        fc1_w columns 1960,1961
#define WS_FLAGA  230336    // [256] int       barrier A flags
#define WS_FLAGB  230592    // [256] int       barrier B flags

#define MAGIC_A 0x5EED0001
#define MAGIC_B 0x5EED0002

// Flags-based grid barrier: requires gridDim.x == blockDim.x == 256 and all
// blocks co-resident (256 blocks on 256 CUs, 4 waves, 1KB LDS -> guaranteed).
// Poison-proof: no counter arithmetic; flag value (magic) != 0xAAAAAAAA != 0.
__device__ __forceinline__ void grid_barrier(int* flags, int magic) {
    __syncthreads();
    if (threadIdx.x == 0) {
        __hip_atomic_store(&flags[blockIdx.x], magic,
                           __ATOMIC_RELEASE, __HIP_MEMORY_SCOPE_AGENT);
    }
    while (__hip_atomic_load(&flags[threadIdx.x],
                             __ATOMIC_ACQUIRE, __HIP_MEMORY_SCOPE_AGENT) != magic) {
        __builtin_amdgcn_s_sleep(1);
    }
    __syncthreads();
}

// ---------------------------------------------------------------------------
// k_pre: conv1 (+prep) | barrier | conv2 | barrier | fc1.  256 blocks x 256.
// ---------------------------------------------------------------------------
__global__ __launch_bounds__(256) void k_pre(
    const float* __restrict__ images,
    const float* __restrict__ c1w, const float* __restrict__ c1b,
    const float* __restrict__ c2w, const float* __restrict__ c2b,
    const float* __restrict__ fc1w, const float* __restrict__ fc1b,
    const float* __restrict__ fc2w,
    const float* __restrict__ A_B, const float* __restrict__ A_C,
    float* __restrict__ ws)
{
    const int b = blockIdx.x, t = threadIdx.x;
    const int g = b * 256 + t;

    // ---- Stage A prep (distributed across the whole grid) ----
    if (g < 8000) {                      // fc2 pack: i = j4*64 + e
        int j4 = g >> 6, e = g & 63;
        float4 v;
        v.x = fc2w[e * 500 + 4 * j4 + 0];
        v.y = fc2w[e * 500 + 4 * j4 + 1];
        v.z = fc2w[e * 500 + 4 * j4 + 2];
        v.w = fc2w[e * 500 + 4 * j4 + 3];
        *(float4*)&ws[WS_FC2P + g * 4] = v;
    } else if (g < 8256) {               // Aflat
        int i = g - 8000;
        ws[WS_AFLAT + i] = A_B[i] + A_C[i];
    } else if (g < 9256) {               // Wx
        int i = g - 8256, j = i >> 1, k = i & 1;
        ws[WS_WX + i] = fc1w[j * 1962 + 1960 + k];
    } else if (g < 22256) {              // zero fc1p for atomics
        ws[WS_FC1P + (g - 9256)] = 0.f;
    }

    // ---- Stage A: conv1 + relu + pool2 (520 virtual blocks) ----
    for (int vb = b; vb < 520; vb += 256) {
        const int c = vb / 20, r = vb - c * 20;
        const int oc = r >> 2, gg = r & 3;
        const int py = gg * 8 + (t >> 5), px = t & 31;

        float wr[25];
#pragma unroll
        for (int i = 0; i < 25; ++i) wr[i] = c1w[oc * 25 + i];
        const float bias = c1b[oc];

        const float* im = images + c * 4624 + (2 * py) * 68 + 2 * px;
        float ir[6][6];
#pragma unroll
        for (int a = 0; a < 6; ++a)
#pragma unroll
            for (int q = 0; q < 3; ++q) {
                float2 v = *(const float2*)&im[a * 68 + 2 * q];
                ir[a][2 * q] = v.x; ir[a][2 * q + 1] = v.y;
            }
        float a00 = bias, a01 = bias, a10 = bias, a11 = bias;
#pragma unroll
        for (int ky = 0; ky < 5; ++ky)
#pragma unroll
            for (int kx = 0; kx < 5; ++kx) {
                float w = wr[ky * 5 + kx];
                a00 += w * ir[ky][kx];     a01 += w * ir[ky][kx + 1];
                a10 += w * ir[ky + 1][kx]; a11 += w * ir[ky + 1][kx + 1];
            }
        float v = fmaxf(fmaxf(fmaxf(a00, a01), fmaxf(a10, a11)), 0.f);
        ws[WS_SC1 + ((c * 5 + oc) * 32 + py) * 32 + px] = v;
    }

    grid_barrier((int*)(ws + WS_FLAGA), MAGIC_A);

    // ---- Stage B: conv2 + relu + pool2 (260 virtual blocks) ----
    __shared__ float sw[125];
    for (int vb = b; vb < 260; vb += 256) {
        const int c = vb / 10, oc = vb - c * 10;
        __syncthreads();
        if (t < 125) sw[t] = c2w[oc * 125 + t];
        __syncthreads();
        if (t < 196) {
            const int py = t / 14, px = t - py * 14;
            const float bias = c2b[oc];
            float a00 = bias, a01 = bias, a10 = bias, a11 = bias;
            const float* base = ws + WS_SC1 + c * 5120 + (2 * py) * 32 + 2 * px;
#pragma unroll
            for (int ic = 0; ic < 5; ++ic) {
                const float* s1 = base + ic * 1024;
                float ir[6][6];
#pragma unroll
                for (int a = 0; a < 6; ++a)
#pragma unroll
                    for (int q = 0; q < 3; ++q) {
                        float2 v = *(const float2*)&s1[a * 32 + 2 * q];
                        ir[a][2 * q] = v.x; ir[a][2 * q + 1] = v.y;
                    }
#pragma unroll
                for (int ky = 0; ky < 5; ++ky)
#pragma unroll
                    for (int kx = 0; kx < 5; ++kx) {
                        float w = sw[ic * 25 + ky * 5 + kx];
                        a00 += w * ir[ky][kx];     a01 += w * ir[ky][kx + 1];
                        a10 += w * ir[ky + 1][kx]; a11 += w * ir[ky + 1][kx + 1];
                    }
            }
            float v = fmaxf(fmaxf(fmaxf(a00, a01), fmaxf(a10, a11)), 0.f);
            ws[WS_FEAT + c * 1960 + oc * 196 + py * 14 + px] = v;
        }
    }

    grid_barrier((int*)(ws + WS_FLAGB), MAGIC_B);

    // ---- Stage C: fc1 (1024 waves; wg<1000: j = wg/2, K-half = wg&1) ----
    const int lane = t & 63;
    const int wg = b * 4 + (t >> 6);
    if (wg < 1000) {
        const int j = wg >> 1, half = wg & 1;
        const int kbase = half * 980;
        float wreg[16];
#pragma unroll
        for (int i = 0; i < 16; ++i) {
            int kl = lane + 64 * i;
            wreg[i] = (kl < 980) ? fc1w[j * 1962 + kbase + kl] : 0.f;
        }
        const float bj = (half == 0) ? fc1b[j] : 0.f;
        const float* feat = ws + WS_FEAT;
        float* fc1p = ws + WS_FC1P;
        for (int c = 0; c < 26; ++c) {
            const float* f = feat + c * 1960 + kbase;
            float acc0 = 0.f, acc1 = 0.f;
#pragma unroll
            for (int i = 0; i < 16; i += 2) {
                int k0 = lane + 64 * i, k1 = lane + 64 * (i + 1);
                acc0 += wreg[i]     * f[(k0 < 980) ? k0 : 0];
                acc1 += wreg[i + 1] * f[(k1 < 980) ? k1 : 0];
            }
            float acc = acc0 + acc1;
#pragma unroll
            for (int off = 32; off >= 1; off >>= 1) acc += __shfl_xor(acc, off);
            if (lane == 0) atomicAdd(&fc1p[c * 500 + j], acc + bj);
        }
    }
}

// ---------------------------------------------------------------------------
// K3: per-sample h = relu(fc1p[cls] + x.Wx) -> fc2 GEMV -> wave softmax ->
// expert-weighted 2x2 combine. 8 samples/block, 1024 blocks. (unchanged)
// ---------------------------------------------------------------------------
__global__ __launch_bounds__(256) void k_moe(
    const float* __restrict__ x, const int* __restrict__ cls,
    const float* __restrict__ fc2b, const float* __restrict__ x_tar,
    const float* __restrict__ ws, float* __restrict__ out)
{
    __shared__ float sh[8][500];
    __shared__ float sred[2048];
    const int t = threadIdx.x;
    const int b0 = blockIdx.x * 8;
    const float* fc1p = ws + WS_FC1P;
    const float* fc2P = ws + WS_FC2P;
    const float* Af   = ws + WS_AFLAT;
    const float* Wx   = ws + WS_WX;

    int cs[8]; float xs0[8], xs1[8];
#pragma unroll
    for (int s = 0; s < 8; ++s) {
        cs[s]  = cls[b0 + s];
        xs0[s] = x[2 * (b0 + s)];
        xs1[s] = x[2 * (b0 + s) + 1];
    }
    for (int j = t; j < 500; j += 256) {
        float2 wx = *(const float2*)&Wx[2 * j];
#pragma unroll
        for (int s = 0; s < 8; ++s) {
            float v = fc1p[cs[s] * 500 + j] + xs0[s] * wx.x + xs1[s] * wx.y;
            sh[s][j] = fmaxf(v, 0.f);
        }
    }
    __syncthreads();

    const int e = t & 63, p = t >> 6;
    float acc[8];
#pragma unroll
    for (int s = 0; s < 8; ++s) acc[s] = 0.f;

    const int gbeg = p * 32;
    const int gend = (p == 3) ? 125 : (gbeg + 32);
    for (int j4 = gbeg; j4 < gend; ++j4) {
        float4 wv = *(const float4*)&fc2P[(j4 * 64 + e) * 4];
#pragma unroll
        for (int s = 0; s < 8; ++s) {
            float4 h4 = *(const float4*)&sh[s][j4 * 4];
            acc[s] += h4.x * wv.x + h4.y * wv.y + h4.z * wv.z + h4.w * wv.w;
        }
    }
#pragma unroll
    for (int s = 0; s < 8; ++s) sred[p * 512 + s * 64 + e] = acc[s];
    __syncthreads();

    const float xt0 = x_tar[0], xt1 = x_tar[1];
    const float be = fc2b[e];
    const float4 a4 = *(const float4*)&Af[4 * e];
#pragma unroll
    for (int half = 0; half < 2; ++half) {
        int s = half * 4 + p;
        float logit = be + sred[s * 64 + e] + sred[512 + s * 64 + e]
                    + sred[1024 + s * 64 + e] + sred[1536 + s * 64 + e];
        float m = logit;
#pragma unroll
        for (int off = 32; off >= 1; off >>= 1) m = fmaxf(m, __shfl_xor(m, off));
        float ex = __expf(logit - m);
        float sum = ex;
        float m0 = ex * a4.x, m1 = ex * a4.y, m2 = ex * a4.z, m3 = ex * a4.w;
#pragma unroll
        for (int off = 32; off >= 1; off >>= 1) {
            sum += __shfl_xor(sum, off);
            m0 += __shfl_xor(m0, off);
            m1 += __shfl_xor(m1, off);
            m2 += __shfl_xor(m2, off);
            m3 += __shfl_xor(m3, off);
        }
        if (e == 0) {
            int bb = b0 + s;
            float d0 = xt0 - x[2 * bb], d1 = xt1 - x[2 * bb + 1];
            float inv = 1.f / sum;
            out[2 * bb]     = (m0 * d0 + m1 * d1) * inv;
            out[2 * bb + 1] = (m2 * d0 + m3 * d1) * inv;
        }
    }
}

extern "C" void kernel_launch(void* const* d_in, const int* in_sizes, int n_in,
                              void* d_out, int out_size, void* d_ws, size_t ws_size,
                              hipStream_t stream) {
    const float* x      = (const float*)d_in[0];
    const int*   cls    = (const int*)  d_in[1];
    const float* images = (const float*)d_in[2];
    const float* c1w    = (const float*)d_in[3];
    const float* c1b    = (const float*)d_in[4];
    const float* c2w    = (const float*)d_in[5];
    const float* c2b    = (const float*)d_in[6];
    const float* fc1w   = (const float*)d_in[7];
    const float* fc1b   = (const float*)d_in[8];
    const float* fc2w   = (const float*)d_in[9];
    const float* fc2b   = (const float*)d_in[10];
    const float* A_B    = (const float*)d_in[11];
    const float* A_C    = (const float*)d_in[12];
    const float* x_tar  = (const float*)d_in[13];
    float* out = (float*)d_out;
    float* ws  = (float*)d_ws;

    k_pre<<<256, 256, 0, stream>>>(images, c1w, c1b, c2w, c2b,
                                   fc1w, fc1b, fc2w, A_B, A_C, ws);
    k_moe<<<1024, 256, 0, stream>>>(x, cls, fc2b, x_tar, ws, out);
}

// Round 4
// 129.527 us; speedup vs baseline: 1.3599x; 1.3599x over previous
//
#include <hip/hip_runtime.h>

// Workspace layout (float offsets), ~925 KB total.
#define WS_SC1    0         // [26][5][32][32] pooled conv1
#define WS_FEAT   133120    // [26][1960]      pooled conv2 (flattened)
#define WS_FC1P   184080    // [26][500]       fc1 class-part + bias
#define WS_FC2P   197080    // [125][64][4]    fc2 weights packed float4 by (j4,e)
#define WS_AFLAT  229080    // [64][4]         A_B + A_C
#define WS_WX     229336    // [500][2]        fc1_w columns 1960,1961

// ---------------------------------------------------------------------------
// K1a: conv1 + relu + pool2. blocks 0..519: (class, oc, row-group); one pooled
// output per thread, weights in SGPRs, image via L1/L2.
// blocks 520,521: prep (fc2 float4 pack; Aflat; Wx).
// ---------------------------------------------------------------------------
__global__ __launch_bounds__(256) void k_conv1(
    const float* __restrict__ images, const float* __restrict__ c1w,
    const float* __restrict__ c1b, const float* __restrict__ fc2w,
    const float* __restrict__ fc1w, const float* __restrict__ A_B,
    const float* __restrict__ A_C, float* __restrict__ ws)
{
    const int b = blockIdx.x, t = threadIdx.x;
    if (b >= 520) {
        if (b == 520) {
            float* P = ws + WS_FC2P;
            for (int i = t; i < 8000; i += 256) {   // i = j4*64 + e
                int j4 = i >> 6, e = i & 63;
                float4 v;
                v.x = fc2w[e * 500 + 4 * j4 + 0];
                v.y = fc2w[e * 500 + 4 * j4 + 1];
                v.z = fc2w[e * 500 + 4 * j4 + 2];
                v.w = fc2w[e * 500 + 4 * j4 + 3];
                *(float4*)&P[i * 4] = v;
            }
        } else {
            float* Af = ws + WS_AFLAT;
            if (t < 256) Af[t] = A_B[t] + A_C[t];
            float* Wx = ws + WS_WX;
            for (int i = t; i < 1000; i += 256) {
                int j = i >> 1, k = i & 1;
                Wx[i] = fc1w[j * 1962 + 1960 + k];
            }
        }
        return;
    }

    const int c = b / 20, r = b - c * 20;
    const int oc = r >> 2, g = r & 3;
    const int py = g * 8 + (t >> 5), px = t & 31;

    float wr[25];
#pragma unroll
    for (int i = 0; i < 25; ++i) wr[i] = c1w[oc * 25 + i];
    const float bias = c1b[oc];

    const float* im = images + c * 4624 + (2 * py) * 68 + 2 * px;
    float ir[6][6];
#pragma unroll
    for (int a = 0; a < 6; ++a)
#pragma unroll
        for (int q = 0; q < 3; ++q) {
            float2 v = *(const float2*)&im[a * 68 + 2 * q];
            ir[a][2 * q] = v.x; ir[a][2 * q + 1] = v.y;
        }

    float a00 = bias, a01 = bias, a10 = bias, a11 = bias;
#pragma unroll
    for (int ky = 0; ky < 5; ++ky)
#pragma unroll
        for (int kx = 0; kx < 5; ++kx) {
            float w = wr[ky * 5 + kx];
            a00 += w * ir[ky][kx];     a01 += w * ir[ky][kx + 1];
            a10 += w * ir[ky + 1][kx]; a11 += w * ir[ky + 1][kx + 1];
        }
    float v = fmaxf(fmaxf(fmaxf(a00, a01), fmaxf(a10, a11)), 0.f);
    ws[WS_SC1 + ((c * 5 + oc) * 32 + py) * 32 + px] = v;
}

// ---------------------------------------------------------------------------
// K1b: conv2 + relu + pool2. 260 blocks = (class, oc); threads 0..195 one
// pooled output each; weights via LDS broadcast, inputs via L1/L2.
// ---------------------------------------------------------------------------
__global__ __launch_bounds__(256) void k_conv2(
    const float* __restrict__ c2w, const float* __restrict__ c2b,
    float* __restrict__ ws)
{
    const int b = blockIdx.x, t = threadIdx.x;
    const int c = b / 10, oc = b - c * 10;

    __shared__ float sw[125];
    if (t < 125) sw[t] = c2w[oc * 125 + t];
    __syncthreads();
    if (t >= 196) return;

    const int py = t / 14, px = t - py * 14;
    const float bias = c2b[oc];
    float a00 = bias, a01 = bias, a10 = bias, a11 = bias;

    const float* base = ws + WS_SC1 + c * 5120 + (2 * py) * 32 + 2 * px;
#pragma unroll
    for (int ic = 0; ic < 5; ++ic) {
        const float* s1 = base + ic * 1024;
        float ir[6][6];
#pragma unroll
        for (int a = 0; a < 6; ++a)
#pragma unroll
            for (int q = 0; q < 3; ++q) {
                float2 v = *(const float2*)&s1[a * 32 + 2 * q];
                ir[a][2 * q] = v.x; ir[a][2 * q + 1] = v.y;
            }
#pragma unroll
        for (int ky = 0; ky < 5; ++ky)
#pragma unroll
            for (int kx = 0; kx < 5; ++kx) {
                float w = sw[ic * 25 + ky * 5 + kx];
                a00 += w * ir[ky][kx];     a01 += w * ir[ky][kx + 1];
                a10 += w * ir[ky + 1][kx]; a11 += w * ir[ky + 1][kx + 1];
            }
    }
    float v = fmaxf(fmaxf(fmaxf(a00, a01), fmaxf(a10, a11)), 0.f);
    ws[WS_FEAT + c * 1960 + oc * 196 + py * 14 + px] = v;
}

// ---------------------------------------------------------------------------
// K2: fc1 restructured for TLP. 1638 blocks = (class c, j-group of 8).
// Each wave computes 2 full j-dots (K=1960), shuffle-reduce, direct store.
// fc1_w rows re-read per class: 102 MB of L2 traffic (~3 us aggregate) traded
// for 6.4 blocks/CU of latency hiding (old: 1 wave/SIMD, fully exposed).
// ---------------------------------------------------------------------------
__global__ __launch_bounds__(256) void k_fc1(
    const float* __restrict__ fc1w, const float* __restrict__ fc1b,
    float* __restrict__ ws)
{
    const int lane = threadIdx.x & 63, w = threadIdx.x >> 6;
    const int c = blockIdx.x / 63, jg = blockIdx.x - c * 63;
    const int j0 = jg * 8 + 2 * w;
    if (j0 >= 500) return;
    const int j1 = j0 + 1;

    const float* f  = ws + WS_FEAT + c * 1960;
    const float* w0 = fc1w + j0 * 1962;
    const float* w1 = fc1w + j1 * 1962;

    float acc0 = 0.f, acc1 = 0.f;
#pragma unroll
    for (int i = 0; i < 30; ++i) {      // k < 1920: no guard needed
        int k = lane + 64 * i;
        float fv = f[k];
        acc0 += w0[k] * fv;
        acc1 += w1[k] * fv;
    }
    {                                    // tail: k in [1920,1960)
        int k = lane + 1920;
        if (k < 1960) {
            float fv = f[k];
            acc0 += w0[k] * fv;
            acc1 += w1[k] * fv;
        }
    }
#pragma unroll
    for (int off = 32; off >= 1; off >>= 1) {
        acc0 += __shfl_xor(acc0, off);
        acc1 += __shfl_xor(acc1, off);
    }
    if (lane == 0) {
        ws[WS_FC1P + c * 500 + j0] = acc0 + fc1b[j0];
        ws[WS_FC1P + c * 500 + j1] = acc1 + fc1b[j1];
    }
}

// ---------------------------------------------------------------------------
// K3: per-sample h = relu(fc1p[cls] + x.Wx) -> fc2 GEMV (packed float4
// weights from L2, broadcast LDS h-reads) -> wave softmax over 64 experts ->
// expert-weighted 2x2 combine. 8 samples/block, 1024 blocks.
// ---------------------------------------------------------------------------
__global__ __launch_bounds__(256) void k_moe(
    const float* __restrict__ x, const int* __restrict__ cls,
    const float* __restrict__ fc2b, const float* __restrict__ x_tar,
    const float* __restrict__ ws, float* __restrict__ out)
{
    __shared__ float sh[8][500];
    __shared__ float sred[2048];
    const int t = threadIdx.x;
    const int b0 = blockIdx.x * 8;
    const float* fc1p = ws + WS_FC1P;
    const float* fc2P = ws + WS_FC2P;
    const float* Af   = ws + WS_AFLAT;
    const float* Wx   = ws + WS_WX;

    int cs[8]; float xs0[8], xs1[8];
#pragma unroll
    for (int s = 0; s < 8; ++s) {
        cs[s]  = cls[b0 + s];
        xs0[s] = x[2 * (b0 + s)];
        xs1[s] = x[2 * (b0 + s) + 1];
    }
    for (int j = t; j < 500; j += 256) {
        float2 wx = *(const float2*)&Wx[2 * j];
#pragma unroll
        for (int s = 0; s < 8; ++s) {
            float v = fc1p[cs[s] * 500 + j] + xs0[s] * wx.x + xs1[s] * wx.y;
            sh[s][j] = fmaxf(v, 0.f);
        }
    }
    __syncthreads();

    const int e = t & 63, p = t >> 6;
    float acc[8];
#pragma unroll
    for (int s = 0; s < 8; ++s) acc[s] = 0.f;

    const int gbeg = p * 32;
    const int gend = (p == 3) ? 125 : (gbeg + 32);
    for (int j4 = gbeg; j4 < gend; ++j4) {
        float4 wv = *(const float4*)&fc2P[(j4 * 64 + e) * 4];
#pragma unroll
        for (int s = 0; s < 8; ++s) {
            float4 h4 = *(const float4*)&sh[s][j4 * 4];
            acc[s] += h4.x * wv.x + h4.y * wv.y + h4.z * wv.z + h4.w * wv.w;
        }
    }
#pragma unroll
    for (int s = 0; s < 8; ++s) sred[p * 512 + s * 64 + e] = acc[s];
    __syncthreads();

    const float xt0 = x_tar[0], xt1 = x_tar[1];
    const float be = fc2b[e];
    const float4 a4 = *(const float4*)&Af[4 * e];
#pragma unroll
    for (int half = 0; half < 2; ++half) {
        int s = half * 4 + p;
        float logit = be + sred[s * 64 + e] + sred[512 + s * 64 + e]
                    + sred[1024 + s * 64 + e] + sred[1536 + s * 64 + e];
        float m = logit;
#pragma unroll
        for (int off = 32; off >= 1; off >>= 1) m = fmaxf(m, __shfl_xor(m, off));
        float ex = __expf(logit - m);
        float sum = ex;
        float m0 = ex * a4.x, m1 = ex * a4.y, m2 = ex * a4.z, m3 = ex * a4.w;
#pragma unroll
        for (int off = 32; off >= 1; off >>= 1) {
            sum += __shfl_xor(sum, off);
            m0 += __shfl_xor(m0, off);
            m1 += __shfl_xor(m1, off);
            m2 += __shfl_xor(m2, off);
            m3 += __shfl_xor(m3, off);
        }
        if (e == 0) {
            int bb = b0 + s;
            float d0 = xt0 - x[2 * bb], d1 = xt1 - x[2 * bb + 1];
            float inv = 1.f / sum;
            out[2 * bb]     = (m0 * d0 + m1 * d1) * inv;
            out[2 * bb + 1] = (m2 * d0 + m3 * d1) * inv;
        }
    }
}

extern "C" void kernel_launch(void* const* d_in, const int* in_sizes, int n_in,
                              void* d_out, int out_size, void* d_ws, size_t ws_size,
                              hipStream_t stream) {
    const float* x      = (const float*)d_in[0];
    const int*   cls    = (const int*)  d_in[1];
    const float* images = (const float*)d_in[2];
    const float* c1w    = (const float*)d_in[3];
    const float* c1b    = (const float*)d_in[4];
    const float* c2w    = (const float*)d_in[5];
    const float* c2b    = (const float*)d_in[6];
    const float* fc1w   = (const float*)d_in[7];
    const float* fc1b   = (const float*)d_in[8];
    const float* fc2w   = (const float*)d_in[9];
    const float* fc2b   = (const float*)d_in[10];
    const float* A_B    = (const float*)d_in[11];
    const float* A_C    = (const float*)d_in[12];
    const float* x_tar  = (const float*)d_in[13];
    float* out = (float*)d_out;
    float* ws  = (float*)d_ws;

    k_conv1<<<522, 256, 0, stream>>>(images, c1w, c1b, fc2w, fc1w, A_B, A_C, ws);
    k_conv2<<<260, 256, 0, stream>>>(c2w, c2b, ws);
    k_fc1  <<<1638, 256, 0, stream>>>(fc1w, fc1b, ws);
    k_moe  <<<1024, 256, 0, stream>>>(x, cls, fc2b, x_tar, ws, out);
}